// Round 13
// baseline (218.384 us; speedup 1.0000x reference)
//
#include <hip/hip_runtime.h>

// ---------------------------------------------------------------------------
// Fused 2-layer LSTM, N=8192, T=28, I=28, H=128, + final [128->10] linear.
// One block = 32 samples through all 28 timesteps of both layers.
// grid = 256 blocks x 512 threads (8 waves) -> 1 block/CU, 2 waves/SIMD.
//
// R13 = R12 (passing, 135.5us) + two issue-cycle trims:
//  (1) acc zero-seed + multiplicative bias: the 64 v_mov/wave/interval of
//      acc-bias init are gone -- each MFMA chain's first MFMA takes a shared
//      loop-invariant ZERO tuple as srcC; bias applies in the activation as
//      sigma(x+b) = rcp(fma(exp2(-x), EB, 1)), EB = exp2(-b^) precomputed
//      (g-gate: exp2(+b^) with the 2log2e scale).  Activation op count is
//      unchanged (the bias-add becomes the fma), so the movs are a net cut.
//  (2) x prefetch one interval ahead (xpk path): xf for t+1 is loaded right
//      after xf(t) is consumed -> full-interval latency cover instead of
//      ~400 cy; drained for free at the barrier.  +8 persistent regs on L0
//      waves only (WRITE_SIZE is the spill watch).
//
// Structure (R11/R12, verified):
//   waves 0-3 = L0 specialists: whh0+wih0 (160 regs), own 32 dims each.
//   waves 4-7 = L1 specialists: whh1 (128 regs); wih1 read from LDS.
// Interval I: L0(t=I) and L1(t=I-1); 29 intervals, ONE barrier each.
// exp2-domain gates (R12): pack_weights pre-scales sigma rows by log2e and
// g rows by 2log2e.  h->bf16 via v_cvt_pk_bf16_f32 (R12).
// Race freedom (h0,h1 double-buffered): see R10/R11 analysis -- unchanged.
// LDS: wih1 131072 + h0 2x8192 + h1 2x8192 = 163840 (gfx950 max).
// ---------------------------------------------------------------------------

typedef short  short8   __attribute__((ext_vector_type(8)));
typedef float  float4_t __attribute__((ext_vector_type(4)));

#define WIH1_OFF 0        // 131072 B : w_ih1, persistent in LDS
#define H0_OFF   131072   // 2 x 8192 B : h0 double buffer
#define H1_OFF   147456   // 2 x 8192 B : h1 double buffer
#define SMEM_SZ  163840   // full 160 KiB LDS (dynamic alloc)

#define WPACK_SHORTS 212992u
#define XPACK_SHORTS 7340032u   // 256 blk x 28 t x 2 mt x 512

#define LOG2E  1.4426950408889634f
#define TLOG2E 2.8853900817779268f

__device__ __forceinline__ unsigned short bf16r(float v) {
  union { float f; unsigned u; } x; x.f = v;
  unsigned r = x.u + 0x7fffu + ((x.u >> 16) & 1u);   // round-to-nearest-even
  return (unsigned short)(r >> 16);
}
__device__ __forceinline__ float bf2f(unsigned short b) {
  union { unsigned u; float f; } x; x.u = ((unsigned)b) << 16;
  return x.f;
}
// exp2-domain activations with multiplicative bias (EB = exp2(-b^)):
// sigma(x+b) = rcp(exp2(-x)*EB + 1)
__device__ __forceinline__ float sig2b(float xs, float eb) {
  return __builtin_amdgcn_rcpf(
      __builtin_fmaf(__builtin_amdgcn_exp2f(-xs), eb, 1.0f));
}
// tanh(g+b) with 2log2e pre-scale; EB2 = exp2(+b^)
__device__ __forceinline__ float tanh2b(float xs, float eb2) {
  return 1.0f - 2.0f * __builtin_amdgcn_rcpf(
      __builtin_fmaf(__builtin_amdgcn_exp2f(xs), eb2, 1.0f));
}
// tanh(c), c natural
__device__ __forceinline__ float tanh2c(float c) {
  return 1.0f - 2.0f * __builtin_amdgcn_rcpf(
      __builtin_amdgcn_exp2f(c * TLOG2E) + 1.0f);
}
// pack two h fp32 -> one dword of 2 bf16 (RTNE) in a single VALU inst
__device__ __forceinline__ unsigned cvt_pk_bf16(float lo, float hi) {
  unsigned u;
  asm("v_cvt_pk_bf16_f32 %0, %1, %2" : "=v"(u) : "v"(lo), "v"(hi));
  return u;
}

// ---------------------------------------------------------------------------
// Prologue: pack weights (fp32 -> bf16) into MFMA B-frag tiled layout in ws,
// pre-scaled into the exp2 domain (i,f,o rows x log2e; g rows x 2log2e).
// ws (unsigned short units):
//   [0      ,16384) : w_ih0  [1 kc][32 tiles][64 lanes][8]  (k padded to 32)
//   [16384  ,81920) : w_hh0  [4 kc][32 tiles][64][8]
//   [81920 ,147456) : w_ih1  [4 kc][32][64][8]
//   [147456,212992) : w_hh1  [4 kc][32][64][8]
// element (tile,lane,j): row = tile*16 + (lane&15), k = kc*32 + (lane>>4)*8 + j
// Gate of a row: tile>>3 (0=i,1=f,2=g,3=o).
// ---------------------------------------------------------------------------
__global__ void pack_weights(const float* __restrict__ wih0, const float* __restrict__ whh0,
                             const float* __restrict__ wih1, const float* __restrict__ whh1,
                             unsigned short* __restrict__ dst)
{
  int e = blockIdx.x * 256 + threadIdx.x;
  const float* src; int K; int i;
  if      (e < 16384)  { src = wih0; K = 28;  i = e;          }
  else if (e < 81920)  { src = whh0; K = 128; i = e - 16384;  }
  else if (e < 147456) { src = wih1; K = 128; i = e - 81920;  }
  else if (e < 212992) { src = whh1; K = 128; i = e - 147456; }
  else return;
  int j = i & 7, lane = (i >> 3) & 63, tile = (i >> 9) & 31, kc = i >> 14;
  int row = tile * 16 + (lane & 15);
  int k = kc * 32 + ((lane >> 4) << 3) + j;
  float v = (k < K) ? src[row * K + k] : 0.0f;
  float s = ((tile >> 3) == 2) ? TLOG2E : LOG2E;
  dst[e] = bf16r(v * s);
}

// ---------------------------------------------------------------------------
// pack_x: x fp32 -> bf16 MFMA A-frag tiles in ws (one dword = 2 shorts/thr).
// Frag (blk,t,mt): 512 shorts; lane holds 8: sample = blk*32+mt*16+(lane&15),
// k = (lane>>4)*8 + j (k padded 28->32 with zeros).  x itself is NOT scaled
// (the exp2 scale lives in the weights).
// ---------------------------------------------------------------------------
__global__ void pack_x(const float* __restrict__ xg, unsigned* __restrict__ dst)
{
  unsigned d = blockIdx.x * 256 + threadIdx.x;      // dword index
  if (d >= XPACK_SHORTS / 2) return;
  unsigned base = d * 2;
  int j    = base & 7;                // even
  int lane = (base >> 3) & 63;
  int mt   = (base >> 9) & 1;
  unsigned bt = base >> 10;           // blk*28 + t
  int t    = bt % 28;
  int blk  = bt / 28;
  int s    = blk * 32 + mt * 16 + (lane & 15);
  int k    = ((lane >> 4) << 3) + j;
  float v0 = 0.f, v1 = 0.f;
  if (k < 28) {                        // k even, so k<28 implies k+1<=27
    const float* xs = xg + (size_t)s * 784 + t * 28 + k;
    v0 = xs[0]; v1 = xs[1];
  }
  dst[d] = (unsigned)bf16r(v0) | ((unsigned)bf16r(v1) << 16);
}

// ---------------------------------------------------------------------------
// Main fused kernel.
// ---------------------------------------------------------------------------
__global__ __launch_bounds__(512, 2)
void lstm_fused(const float* __restrict__ xg,
                const unsigned short* __restrict__ wpack,
                const unsigned short* __restrict__ xpk,   // may be null
                const float* __restrict__ bih0, const float* __restrict__ bhh0,
                const float* __restrict__ bih1, const float* __restrict__ bhh1,
                const float* __restrict__ wout, const float* __restrict__ bout,
                float* __restrict__ out)
{
  extern __shared__ __align__(16) char smem[];

  const int tid  = threadIdx.x;
  const int lane = tid & 63;
  const int wave = tid >> 6;          // 0..7
  const bool isL0 = (wave < 4);
  const int gw   = wave & 3;          // role-local: owns dims [gw*32, gw*32+32)
  const int q    = lane >> 4;         // quad: acc rows q*4 .. q*4+3
  const int mcol = lane & 15;         // acc col = h-dim within 16-dim group
  const int n0   = blockIdx.x * 32;   // batch tile base

  const short8* wp = (const short8*)wpack;

  // ---- persistent weights (role-specific) -------------------------------
  // L0 wave: whh0 for 2 dim-groups (128) + wih0 (32) = 160 regs.
  // L1 wave: whh1 for 2 dim-groups (128) regs; wih1 comes from LDS.
  short8 W[2][4][4];    // [dgi][kc][g]
  short8 WX[2][4];      // wih0 [dgi][g], L0 only
  if (isL0) {
#pragma unroll
    for (int dgi = 0; dgi < 2; ++dgi) {
      int dg = gw * 2 + dgi;
#pragma unroll
      for (int g = 0; g < 4; ++g)
        WX[dgi][g] = wp[(g * 8 + dg) * 64 + lane];
#pragma unroll
      for (int kc = 0; kc < 4; ++kc)
#pragma unroll
        for (int g = 0; g < 4; ++g)
          W[dgi][kc][g] = wp[ 2048 + (kc * 32 + g * 8 + dg) * 64 + lane];
    }
  } else {
#pragma unroll
    for (int dgi = 0; dgi < 2; ++dgi) {
      int dg = gw * 2 + dgi;
#pragma unroll
      for (int kc = 0; kc < 4; ++kc)
#pragma unroll
        for (int g = 0; g < 4; ++g)
          W[dgi][kc][g] = wp[18432 + (kc * 32 + g * 8 + dg) * 64 + lane];
    }
  }

  // ---- persistent w_ih1 in LDS (131072 B) --------------------------------
  {
    short8* dstp = (short8*)smem;
#pragma unroll
    for (int rr = 0; rr < 16; ++rr)
      dstp[rr * 512 + tid] = wp[10240 + rr * 512 + tid];
  }

  // ---- role bias multipliers: EB = exp2(-b^) for i,f,o; exp2(+b^) for g --
  float eb[2][4];
#pragma unroll
  for (int dgi = 0; dgi < 2; ++dgi) {
    const int d = (gw * 2 + dgi) * 16 + mcol;
#pragma unroll
    for (int g = 0; g < 4; ++g) {
      float b = isL0 ? (bih0[g * 128 + d] + bhh0[g * 128 + d])
                     : (bih1[g * 128 + d] + bhh1[g * 128 + d]);
      eb[dgi][g] = (g == 2) ? __builtin_amdgcn_exp2f(b * TLOG2E)
                            : __builtin_amdgcn_exp2f(-b * LOG2E);
    }
  }

  // ---- zero the "B" halves of h0/h1 (read as h_{-1}) ---------------------
  {
    int* z0 = (int*)(smem + H0_OFF + 8192);
    int* z1 = (int*)(smem + H1_OFF + 8192);
#pragma unroll
    for (int rr = 0; rr < 4; ++rr) { z0[rr * 512 + tid] = 0; z1[rr * 512 + tid] = 0; }
  }

  __syncthreads();   // wih1 + zeros visible

  const short8* W1f = (const short8*)(smem + WIH1_OFF);
  const short8* XP  = (const short8*)xpk;

  // per-lane constant h-write addresses for the wave's two dim-groups:
  int hconst[2];
#pragma unroll
  for (int dgi = 0; dgi < 2; ++dgi)
    hconst[dgi] = gw * 1024 + (((dgi << 1) | (mcol >> 3)) * 256) + q * 64 + (mcol & 7) * 2;

  float cc[2][2][4] = {{{0.f,0.f,0.f,0.f},{0.f,0.f,0.f,0.f}},
                       {{0.f,0.f,0.f,0.f},{0.f,0.f,0.f,0.f}}};

  // shared zero tuple: srcC of the first MFMA in every chain (loop-invariant)
  const float4_t ZERO = (float4_t){0.f, 0.f, 0.f, 0.f};

  // xf prefetch registers (L0 + xpk path): loaded one interval ahead.
  short8 xf[2];
  if (isL0 && xpk) {
#pragma unroll
    for (int mt = 0; mt < 2; ++mt)
      xf[mt] = XP[((blockIdx.x * 28 + 0) * 2 + mt) * 64 + lane];
  }

#pragma unroll 1
  for (int I = 0; I < 29; ++I) {
    if (isL0) {
      if (I < 28) {
        // ---- LAYER 0, t = I: gates = h0_{t-1}@Whh0^T + x_t@Wih0^T (b in act)
        const short8* H0R = (const short8*)(smem + H0_OFF + (((I + 1) & 1) << 13));
        char*         h0w = smem + H0_OFF + ((I & 1) << 13);

        short8 xuse[2];
        if (xpk) {
          xuse[0] = xf[0]; xuse[1] = xf[1];
        } else {
#pragma unroll
          for (int mt = 0; mt < 2; ++mt) {
            const float* xsrc = xg + (size_t)(n0 + mt * 16 + mcol) * 784 + I * 28 + q * 8;
            float4_t xa = *(const float4_t*)xsrc;
            const float* x2 = xsrc + ((q == 3) ? 0 : 4);
            float4_t xb = *(const float4_t*)x2;
            if (q == 3) xb = (float4_t){0.f, 0.f, 0.f, 0.f};
            short8 f;
#pragma unroll
            for (int j = 0; j < 4; ++j) {
              f[j]     = (short)bf16r(xa[j]);
              f[j + 4] = (short)bf16r(xb[j]);
            }
            xuse[mt] = f;
          }
        }
        // prefetch xf for t+1: full-interval latency cover, drains at barrier
        if (xpk && I < 27) {
#pragma unroll
          for (int mt = 0; mt < 2; ++mt)
            xf[mt] = XP[((blockIdx.x * 28 + I + 1) * 2 + mt) * 64 + lane];
        }

#pragma unroll
        for (int dgi = 0; dgi < 2; ++dgi)
#pragma unroll
          for (int mt = 0; mt < 2; ++mt) {
            float4_t acc[4];
#pragma unroll
            for (int kc = 0; kc < 4; ++kc) {
              short8 hf = H0R[(mt * 4 + kc) * 64 + lane];
#pragma unroll
              for (int g = 0; g < 4; ++g)
                acc[g] = __builtin_amdgcn_mfma_f32_16x16x32_bf16(
                    hf, W[dgi][kc][g], (kc == 0) ? ZERO : acc[g], 0, 0, 0);
            }
#pragma unroll
            for (int g = 0; g < 4; ++g)
              acc[g] = __builtin_amdgcn_mfma_f32_16x16x32_bf16(xuse[mt], WX[dgi][g], acc[g], 0, 0, 0);
            // activations (exp2-domain, multiplicative bias); write h0_t
            float hv[4];
#pragma unroll
            for (int r = 0; r < 4; ++r) {
              float c = sig2b(acc[1][r], eb[dgi][1]) * cc[dgi][mt][r]
                      + sig2b(acc[0][r], eb[dgi][0]) * tanh2b(acc[2][r], eb[dgi][2]);
              cc[dgi][mt][r] = c;
              hv[r] = sig2b(acc[3][r], eb[dgi][3]) * tanh2c(c);
            }
            unsigned u01 = cvt_pk_bf16(hv[0], hv[1]);
            unsigned u23 = cvt_pk_bf16(hv[2], hv[3]);
            char* base = h0w + mt * 4096 + hconst[dgi];
            *(unsigned short*)(base +  0) = (unsigned short)u01;
            *(unsigned short*)(base + 16) = (unsigned short)(u01 >> 16);
            *(unsigned short*)(base + 32) = (unsigned short)u23;
            *(unsigned short*)(base + 48) = (unsigned short)(u23 >> 16);
          }
      }
    } else {
      if (I > 0) {
        // ---- LAYER 1, t = I-1: gates = h1_{t-1}@Whh1^T + h0_t@Wih1^T (+b) -
        const short8* H0S = (const short8*)(smem + H0_OFF + (((I - 1) & 1) << 13));
        const short8* H1R = (const short8*)(smem + H1_OFF + ((I & 1) << 13));
        char*         h1w = smem + H1_OFF + (((I - 1) & 1) << 13);
#pragma unroll
        for (int dgi = 0; dgi < 2; ++dgi) {
          int dg = gw * 2 + dgi;
          float4_t acc[2][4];
          // reg-weight whh1 MFMAs first (kc==0 seeds with ZERO)
#pragma unroll
          for (int kc = 0; kc < 4; ++kc)
#pragma unroll
            for (int mt = 0; mt < 2; ++mt) {
              short8 hf = H1R[(mt * 4 + kc) * 64 + lane];
#pragma unroll
              for (int g = 0; g < 4; ++g)
                acc[mt][g] = __builtin_amdgcn_mfma_f32_16x16x32_bf16(
                    hf, W[dgi][kc][g], (kc == 0) ? ZERO : acc[mt][g], 0, 0, 0);
            }
          // wih1 from LDS
#pragma unroll
          for (int kc = 0; kc < 4; ++kc) {
            short8 wf[4];
#pragma unroll
            for (int g = 0; g < 4; ++g)
              wf[g] = W1f[(kc * 32 + g * 8 + dg) * 64 + lane];
#pragma unroll
            for (int mt = 0; mt < 2; ++mt) {
              short8 hf = H0S[(mt * 4 + kc) * 64 + lane];
#pragma unroll
              for (int g = 0; g < 4; ++g)
                acc[mt][g] = __builtin_amdgcn_mfma_f32_16x16x32_bf16(hf, wf[g], acc[mt][g], 0, 0, 0);
            }
          }
          // activations; write h1_t directly (race-free)
#pragma unroll
          for (int mt = 0; mt < 2; ++mt) {
            float hv[4];
#pragma unroll
            for (int r = 0; r < 4; ++r) {
              float c = sig2b(acc[mt][1][r], eb[dgi][1]) * cc[dgi][mt][r]
                      + sig2b(acc[mt][0][r], eb[dgi][0]) * tanh2b(acc[mt][2][r], eb[dgi][2]);
              cc[dgi][mt][r] = c;
              hv[r] = sig2b(acc[mt][3][r], eb[dgi][3]) * tanh2c(c);
            }
            unsigned u01 = cvt_pk_bf16(hv[0], hv[1]);
            unsigned u23 = cvt_pk_bf16(hv[2], hv[3]);
            char* base = h1w + mt * 4096 + hconst[dgi];
            *(unsigned short*)(base +  0) = (unsigned short)u01;
            *(unsigned short*)(base + 16) = (unsigned short)(u01 >> 16);
            *(unsigned short*)(base + 32) = (unsigned short)u23;
            *(unsigned short*)(base + 48) = (unsigned short)(u23 >> 16);
          }
        }
      }
    }
    __syncthreads();   // THE barrier: ends interval I
  }

  // ================= epilogue: out[s][o] = h1 . wout[o] + bout[o] =========
  // h1(27) was written in interval 28 to buffer 1.
  if (tid < 320) {
    const short8* H1f = (const short8*)(smem + H1_OFF + 8192);
    int s = tid / 10, o = tid - (tid / 10) * 10;
    float sum = bout[o];
#pragma unroll
    for (int kc = 0; kc < 4; ++kc)
#pragma unroll
      for (int sb = 0; sb < 4; ++sb) {
        short8 hv = H1f[((s >> 4) * 4 + kc) * 64 + sb * 16 + (s & 15)];
        int dbase = kc * 32 + sb * 8;
        float4_t w0 = *(const float4_t*)(wout + o * 128 + dbase);
        float4_t w1 = *(const float4_t*)(wout + o * 128 + dbase + 4);
#pragma unroll
        for (int j = 0; j < 4; ++j) {
          sum += bf2f((unsigned short)hv[j])     * w0[j];
          sum += bf2f((unsigned short)hv[j + 4]) * w1[j];
        }
      }
    out[(size_t)(n0 + s) * 10 + o] = sum;
  }
}

extern "C" void kernel_launch(void* const* d_in, const int* in_sizes, int n_in,
                              void* d_out, int out_size, void* d_ws, size_t ws_size,
                              hipStream_t stream) {
  const float* x    = (const float*)d_in[0];
  const float* wih0 = (const float*)d_in[1];
  const float* whh0 = (const float*)d_in[2];
  const float* bih0 = (const float*)d_in[3];
  const float* bhh0 = (const float*)d_in[4];
  const float* wih1 = (const float*)d_in[5];
  const float* whh1 = (const float*)d_in[6];
  const float* bih1 = (const float*)d_in[7];
  const float* bhh1 = (const float*)d_in[8];
  const float* wout = (const float*)d_in[9];
  const float* bout = (const float*)d_in[10];

  unsigned short* wp = (unsigned short*)d_ws;
  const size_t need = (size_t)(WPACK_SHORTS + XPACK_SHORTS) * 2;   // 15.1 MB

  pack_weights<<<832, 256, 0, stream>>>(wih0, whh0, wih1, whh1, wp);

  const unsigned short* xpk = nullptr;
  if (ws_size >= need) {
    unsigned short* xp = wp + WPACK_SHORTS;
    pack_x<<<(XPACK_SHORTS / 2 + 255) / 256, 256, 0, stream>>>(x, (unsigned*)xp);
    xpk = xp;
  }

  lstm_fused<<<256, 512, SMEM_SZ, stream>>>(x, wp, xpk, bih0, bhh0, bih1, bhh1,
                                            wout, bout, (float*)d_out);
}

// Round 14
// 206.970 us; speedup vs baseline: 1.0551x; 1.0551x over previous
//
#include <hip/hip_runtime.h>

// ---------------------------------------------------------------------------
// Fused 2-layer LSTM, N=8192, T=28, I=28, H=128, + final [128->10] linear.
// One block = 32 samples through all 28 timesteps of both layers.
// grid = 256 blocks x 512 threads (8 waves) -> 1 block/CU, 2 waves/SIMD.
//
// R14 = R12 (passing, 135.5us -- the session best) + s_setprio around MFMA
// chains.  R13's two issue-count trims added ~12us of PURE STALL (absolute
// VALU/MFMA cycles identical to R12) -> reverted; the regime is
// stall-dominated, so R14 applies the stall-class lever: T5 setprio.
// Prerequisite check: since R11 each SIMD holds one L0-specialist and one
// L1-specialist wave that are ALWAYS at different phases (role-split
// pipeline) -- exactly the regime where setprio paid (+4-25%) vs the
// lockstep null.  MFMA clusters run at prio 1; activations/staging at 0.
//
// Structure (R11/R12, verified):
//   waves 0-3 = L0 specialists: whh0+wih0 (160 regs), own 32 dims each.
//   waves 4-7 = L1 specialists: whh1 (128 regs); wih1 read from LDS.
// Interval I: L0(t=I) and L1(t=I-1); 29 intervals, ONE barrier each.
// exp2-domain gates (R12): pack_weights pre-scales sigma rows by log2e and
// g rows by 2log2e.  h->bf16 via v_cvt_pk_bf16_f32 (R12).
// Race freedom (h0,h1 double-buffered): see R10/R11 analysis -- unchanged.
// LDS: wih1 131072 + h0 2x8192 + h1 2x8192 = 163840 (gfx950 max).
// ---------------------------------------------------------------------------

typedef short  short8   __attribute__((ext_vector_type(8)));
typedef float  float4_t __attribute__((ext_vector_type(4)));

#define WIH1_OFF 0        // 131072 B : w_ih1, persistent in LDS
#define H0_OFF   131072   // 2 x 8192 B : h0 double buffer
#define H1_OFF   147456   // 2 x 8192 B : h1 double buffer
#define SMEM_SZ  163840   // full 160 KiB LDS (dynamic alloc)

#define WPACK_SHORTS 212992u
#define XPACK_SHORTS 7340032u   // 256 blk x 28 t x 2 mt x 512

#define LOG2E  1.4426950408889634f
#define TLOG2E 2.8853900817779268f

__device__ __forceinline__ unsigned short bf16r(float v) {
  union { float f; unsigned u; } x; x.f = v;
  unsigned r = x.u + 0x7fffu + ((x.u >> 16) & 1u);   // round-to-nearest-even
  return (unsigned short)(r >> 16);
}
__device__ __forceinline__ float bf2f(unsigned short b) {
  union { unsigned u; float f; } x; x.u = ((unsigned)b) << 16;
  return x.f;
}
// exp2-domain activations: xs = x * log2e (pre-scaled into weights/bias).
__device__ __forceinline__ float sig2(float xs) {
  return __builtin_amdgcn_rcpf(1.0f + __builtin_amdgcn_exp2f(-xs));
}
// xs = 2x * log2e (g-gate rows pre-scaled by 2*log2e)
__device__ __forceinline__ float tanh2(float xs) {
  return 1.0f - 2.0f * __builtin_amdgcn_rcpf(__builtin_amdgcn_exp2f(xs) + 1.0f);
}
// pack two h fp32 -> one dword of 2 bf16 (RTNE) in a single VALU inst
__device__ __forceinline__ unsigned cvt_pk_bf16(float lo, float hi) {
  unsigned u;
  asm("v_cvt_pk_bf16_f32 %0, %1, %2" : "=v"(u) : "v"(lo), "v"(hi));
  return u;
}

// ---------------------------------------------------------------------------
// Prologue: pack weights (fp32 -> bf16) into MFMA B-frag tiled layout in ws,
// pre-scaled into the exp2 domain (i,f,o rows x log2e; g rows x 2log2e).
// ws (unsigned short units):
//   [0      ,16384) : w_ih0  [1 kc][32 tiles][64 lanes][8]  (k padded to 32)
//   [16384  ,81920) : w_hh0  [4 kc][32 tiles][64][8]
//   [81920 ,147456) : w_ih1  [4 kc][32][64][8]
//   [147456,212992) : w_hh1  [4 kc][32][64][8]
// element (tile,lane,j): row = tile*16 + (lane&15), k = kc*32 + (lane>>4)*8 + j
// Gate of a row: tile>>3 (0=i,1=f,2=g,3=o).
// ---------------------------------------------------------------------------
__global__ void pack_weights(const float* __restrict__ wih0, const float* __restrict__ whh0,
                             const float* __restrict__ wih1, const float* __restrict__ whh1,
                             unsigned short* __restrict__ dst)
{
  int e = blockIdx.x * 256 + threadIdx.x;
  const float* src; int K; int i;
  if      (e < 16384)  { src = wih0; K = 28;  i = e;          }
  else if (e < 81920)  { src = whh0; K = 128; i = e - 16384;  }
  else if (e < 147456) { src = wih1; K = 128; i = e - 81920;  }
  else if (e < 212992) { src = whh1; K = 128; i = e - 147456; }
  else return;
  int j = i & 7, lane = (i >> 3) & 63, tile = (i >> 9) & 31, kc = i >> 14;
  int row = tile * 16 + (lane & 15);
  int k = kc * 32 + ((lane >> 4) << 3) + j;
  float v = (k < K) ? src[row * K + k] : 0.0f;
  float s = ((tile >> 3) == 2) ? TLOG2E : LOG2E;
  dst[e] = bf16r(v * s);
}

// ---------------------------------------------------------------------------
// pack_x: x fp32 -> bf16 MFMA A-frag tiles in ws (one dword = 2 shorts/thr).
// Frag (blk,t,mt): 512 shorts; lane holds 8: sample = blk*32+mt*16+(lane&15),
// k = (lane>>4)*8 + j (k padded 28->32 with zeros).  x itself is NOT scaled
// (the exp2 scale lives in the weights).
// ---------------------------------------------------------------------------
__global__ void pack_x(const float* __restrict__ xg, unsigned* __restrict__ dst)
{
  unsigned d = blockIdx.x * 256 + threadIdx.x;      // dword index
  if (d >= XPACK_SHORTS / 2) return;
  unsigned base = d * 2;
  int j    = base & 7;                // even
  int lane = (base >> 3) & 63;
  int mt   = (base >> 9) & 1;
  unsigned bt = base >> 10;           // blk*28 + t
  int t    = bt % 28;
  int blk  = bt / 28;
  int s    = blk * 32 + mt * 16 + (lane & 15);
  int k    = ((lane >> 4) << 3) + j;
  float v0 = 0.f, v1 = 0.f;
  if (k < 28) {                        // k even, so k<28 implies k+1<=27
    const float* xs = xg + (size_t)s * 784 + t * 28 + k;
    v0 = xs[0]; v1 = xs[1];
  }
  dst[d] = (unsigned)bf16r(v0) | ((unsigned)bf16r(v1) << 16);
}

// ---------------------------------------------------------------------------
// Main fused kernel.
// ---------------------------------------------------------------------------
__global__ __launch_bounds__(512, 2)
void lstm_fused(const float* __restrict__ xg,
                const unsigned short* __restrict__ wpack,
                const unsigned short* __restrict__ xpk,   // may be null
                const float* __restrict__ bih0, const float* __restrict__ bhh0,
                const float* __restrict__ bih1, const float* __restrict__ bhh1,
                const float* __restrict__ wout, const float* __restrict__ bout,
                float* __restrict__ out)
{
  extern __shared__ __align__(16) char smem[];

  const int tid  = threadIdx.x;
  const int lane = tid & 63;
  const int wave = tid >> 6;          // 0..7
  const bool isL0 = (wave < 4);
  const int gw   = wave & 3;          // role-local: owns dims [gw*32, gw*32+32)
  const int q    = lane >> 4;         // quad: acc rows q*4 .. q*4+3
  const int mcol = lane & 15;         // acc col = h-dim within 16-dim group
  const int n0   = blockIdx.x * 32;   // batch tile base

  const short8* wp = (const short8*)wpack;

  // ---- persistent weights (role-specific) -------------------------------
  // L0 wave: whh0 for 2 dim-groups (128) + wih0 (32) = 160 regs.
  // L1 wave: whh1 for 2 dim-groups (128) regs; wih1 comes from LDS.
  short8 W[2][4][4];    // [dgi][kc][g]
  short8 WX[2][4];      // wih0 [dgi][g], L0 only
  if (isL0) {
#pragma unroll
    for (int dgi = 0; dgi < 2; ++dgi) {
      int dg = gw * 2 + dgi;
#pragma unroll
      for (int g = 0; g < 4; ++g)
        WX[dgi][g] = wp[(g * 8 + dg) * 64 + lane];
#pragma unroll
      for (int kc = 0; kc < 4; ++kc)
#pragma unroll
        for (int g = 0; g < 4; ++g)
          W[dgi][kc][g] = wp[ 2048 + (kc * 32 + g * 8 + dg) * 64 + lane];
    }
  } else {
#pragma unroll
    for (int dgi = 0; dgi < 2; ++dgi) {
      int dg = gw * 2 + dgi;
#pragma unroll
      for (int kc = 0; kc < 4; ++kc)
#pragma unroll
        for (int g = 0; g < 4; ++g)
          W[dgi][kc][g] = wp[18432 + (kc * 32 + g * 8 + dg) * 64 + lane];
    }
  }

  // ---- persistent w_ih1 in LDS (131072 B) --------------------------------
  {
    short8* dstp = (short8*)smem;
#pragma unroll
    for (int rr = 0; rr < 16; ++rr)
      dstp[rr * 512 + tid] = wp[10240 + rr * 512 + tid];
  }

  // ---- role biases (exp2-domain scaled; gate g, dgi dim-group) -----------
  float bias[2][4];
#pragma unroll
  for (int dgi = 0; dgi < 2; ++dgi) {
    const int d = (gw * 2 + dgi) * 16 + mcol;
#pragma unroll
    for (int g = 0; g < 4; ++g) {
      float b = isL0 ? (bih0[g * 128 + d] + bhh0[g * 128 + d])
                     : (bih1[g * 128 + d] + bhh1[g * 128 + d]);
      bias[dgi][g] = b * ((g == 2) ? TLOG2E : LOG2E);
    }
  }

  // ---- zero the "B" halves of h0/h1 (read as h_{-1}) ---------------------
  {
    int* z0 = (int*)(smem + H0_OFF + 8192);
    int* z1 = (int*)(smem + H1_OFF + 8192);
#pragma unroll
    for (int rr = 0; rr < 4; ++rr) { z0[rr * 512 + tid] = 0; z1[rr * 512 + tid] = 0; }
  }

  __syncthreads();   // wih1 + zeros visible

  const short8* W1f = (const short8*)(smem + WIH1_OFF);
  const short8* XP  = (const short8*)xpk;

  // per-lane constant h-write addresses for the wave's two dim-groups:
  int hconst[2];
#pragma unroll
  for (int dgi = 0; dgi < 2; ++dgi)
    hconst[dgi] = gw * 1024 + (((dgi << 1) | (mcol >> 3)) * 256) + q * 64 + (mcol & 7) * 2;

  float cc[2][2][4] = {{{0.f,0.f,0.f,0.f},{0.f,0.f,0.f,0.f}},
                       {{0.f,0.f,0.f,0.f},{0.f,0.f,0.f,0.f}}};

#pragma unroll 1
  for (int I = 0; I < 29; ++I) {
    if (isL0) {
      if (I < 28) {
        // ---- LAYER 0, t = I: gates = b0 + h0_{t-1}@Whh0^T + x_t@Wih0^T ----
        const short8* H0R = (const short8*)(smem + H0_OFF + (((I + 1) & 1) << 13));
        char*         h0w = smem + H0_OFF + ((I & 1) << 13);

        short8 xf[2];
        if (xpk) {
#pragma unroll
          for (int mt = 0; mt < 2; ++mt)
            xf[mt] = XP[((blockIdx.x * 28 + I) * 2 + mt) * 64 + lane];
        } else {
#pragma unroll
          for (int mt = 0; mt < 2; ++mt) {
            const float* xsrc = xg + (size_t)(n0 + mt * 16 + mcol) * 784 + I * 28 + q * 8;
            float4_t xa = *(const float4_t*)xsrc;
            const float* x2 = xsrc + ((q == 3) ? 0 : 4);
            float4_t xb = *(const float4_t*)x2;
            if (q == 3) xb = (float4_t){0.f, 0.f, 0.f, 0.f};
            short8 f;
#pragma unroll
            for (int j = 0; j < 4; ++j) {
              f[j]     = (short)bf16r(xa[j]);
              f[j + 4] = (short)bf16r(xb[j]);
            }
            xf[mt] = f;
          }
        }

#pragma unroll
        for (int dgi = 0; dgi < 2; ++dgi)
#pragma unroll
          for (int mt = 0; mt < 2; ++mt) {
            float4_t acc[4];
#pragma unroll
            for (int g = 0; g < 4; ++g)
              acc[g] = (float4_t){bias[dgi][g], bias[dgi][g], bias[dgi][g], bias[dgi][g]};
            // MFMA cluster at raised priority: the co-resident L1 wave is in
            // a different phase; prio 1 wins issue arbitration for the
            // matrix pipe while our chain is hot (T5, role-split regime).
            __builtin_amdgcn_s_setprio(1);
#pragma unroll
            for (int kc = 0; kc < 4; ++kc) {
              short8 hf = H0R[(mt * 4 + kc) * 64 + lane];
#pragma unroll
              for (int g = 0; g < 4; ++g)
                acc[g] = __builtin_amdgcn_mfma_f32_16x16x32_bf16(hf, W[dgi][kc][g], acc[g], 0, 0, 0);
            }
#pragma unroll
            for (int g = 0; g < 4; ++g)
              acc[g] = __builtin_amdgcn_mfma_f32_16x16x32_bf16(xf[mt], WX[dgi][g], acc[g], 0, 0, 0);
            __builtin_amdgcn_s_setprio(0);
            // activations (exp2-domain gates); write h0_t (race-free)
            float hv[4];
#pragma unroll
            for (int r = 0; r < 4; ++r) {
              float c = sig2(acc[1][r]) * cc[dgi][mt][r] + sig2(acc[0][r]) * tanh2(acc[2][r]);
              cc[dgi][mt][r] = c;
              hv[r] = sig2(acc[3][r]) * tanh2(c * TLOG2E);
            }
            unsigned u01 = cvt_pk_bf16(hv[0], hv[1]);
            unsigned u23 = cvt_pk_bf16(hv[2], hv[3]);
            char* base = h0w + mt * 4096 + hconst[dgi];
            *(unsigned short*)(base +  0) = (unsigned short)u01;
            *(unsigned short*)(base + 16) = (unsigned short)(u01 >> 16);
            *(unsigned short*)(base + 32) = (unsigned short)u23;
            *(unsigned short*)(base + 48) = (unsigned short)(u23 >> 16);
          }
      }
    } else {
      if (I > 0) {
        // ---- LAYER 1, t = I-1: gates = b1 + h1_{t-1}@Whh1^T + h0_t@Wih1^T -
        const short8* H0S = (const short8*)(smem + H0_OFF + (((I - 1) & 1) << 13));
        const short8* H1R = (const short8*)(smem + H1_OFF + ((I & 1) << 13));
        char*         h1w = smem + H1_OFF + (((I - 1) & 1) << 13);
#pragma unroll
        for (int dgi = 0; dgi < 2; ++dgi) {
          int dg = gw * 2 + dgi;
          float4_t acc[2][4];
#pragma unroll
          for (int mt = 0; mt < 2; ++mt)
#pragma unroll
            for (int g = 0; g < 4; ++g)
              acc[mt][g] = (float4_t){bias[dgi][g], bias[dgi][g], bias[dgi][g], bias[dgi][g]};
          __builtin_amdgcn_s_setprio(1);   // MFMA cluster (T5)
          // reg-weight whh1 MFMAs first
#pragma unroll
          for (int kc = 0; kc < 4; ++kc)
#pragma unroll
            for (int mt = 0; mt < 2; ++mt) {
              short8 hf = H1R[(mt * 4 + kc) * 64 + lane];
#pragma unroll
              for (int g = 0; g < 4; ++g)
                acc[mt][g] = __builtin_amdgcn_mfma_f32_16x16x32_bf16(hf, W[dgi][kc][g], acc[mt][g], 0, 0, 0);
            }
          // wih1 from LDS
#pragma unroll
          for (int kc = 0; kc < 4; ++kc) {
            short8 wf[4];
#pragma unroll
            for (int g = 0; g < 4; ++g)
              wf[g] = W1f[(kc * 32 + g * 8 + dg) * 64 + lane];
#pragma unroll
            for (int mt = 0; mt < 2; ++mt) {
              short8 hf = H0S[(mt * 4 + kc) * 64 + lane];
#pragma unroll
              for (int g = 0; g < 4; ++g)
                acc[mt][g] = __builtin_amdgcn_mfma_f32_16x16x32_bf16(hf, wf[g], acc[mt][g], 0, 0, 0);
            }
          }
          __builtin_amdgcn_s_setprio(0);
          // activations; write h1_t directly (race-free)
#pragma unroll
          for (int mt = 0; mt < 2; ++mt) {
            float hv[4];
#pragma unroll
            for (int r = 0; r < 4; ++r) {
              float c = sig2(acc[mt][1][r]) * cc[dgi][mt][r] + sig2(acc[mt][0][r]) * tanh2(acc[mt][2][r]);
              cc[dgi][mt][r] = c;
              hv[r] = sig2(acc[mt][3][r]) * tanh2(c * TLOG2E);
            }
            unsigned u01 = cvt_pk_bf16(hv[0], hv[1]);
            unsigned u23 = cvt_pk_bf16(hv[2], hv[3]);
            char* base = h1w + mt * 4096 + hconst[dgi];
            *(unsigned short*)(base +  0) = (unsigned short)u01;
            *(unsigned short*)(base + 16) = (unsigned short)(u01 >> 16);
            *(unsigned short*)(base + 32) = (unsigned short)u23;
            *(unsigned short*)(base + 48) = (unsigned short)(u23 >> 16);
          }
        }
      }
    }
    __syncthreads();   // THE barrier: ends interval I
  }

  // ================= epilogue: out[s][o] = h1 . wout[o] + bout[o] =========
  // h1(27) was written in interval 28 to buffer 1.
  if (tid < 320) {
    const short8* H1f = (const short8*)(smem + H1_OFF + 8192);
    int s = tid / 10, o = tid - (tid / 10) * 10;
    float sum = bout[o];
#pragma unroll
    for (int kc = 0; kc < 4; ++kc)
#pragma unroll
      for (int sb = 0; sb < 4; ++sb) {
        short8 hv = H1f[((s >> 4) * 4 + kc) * 64 + sb * 16 + (s & 15)];
        int dbase = kc * 32 + sb * 8;
        float4_t w0 = *(const float4_t*)(wout + o * 128 + dbase);
        float4_t w1 = *(const float4_t*)(wout + o * 128 + dbase + 4);
#pragma unroll
        for (int j = 0; j < 4; ++j) {
          sum += bf2f((unsigned short)hv[j])     * w0[j];
          sum += bf2f((unsigned short)hv[j + 4]) * w1[j];
        }
      }
    out[(size_t)(n0 + s) * 10 + o] = sum;
  }
}

extern "C" void kernel_launch(void* const* d_in, const int* in_sizes, int n_in,
                              void* d_out, int out_size, void* d_ws, size_t ws_size,
                              hipStream_t stream) {
  const float* x    = (const float*)d_in[0];
  const float* wih0 = (const float*)d_in[1];
  const float* whh0 = (const float*)d_in[2];
  const float* bih0 = (const float*)d_in[3];
  const float* bhh0 = (const float*)d_in[4];
  const float* wih1 = (const float*)d_in[5];
  const float* whh1 = (const float*)d_in[6];
  const float* bih1 = (const float*)d_in[7];
  const float* bhh1 = (const float*)d_in[8];
  const float* wout = (const float*)d_in[9];
  const float* bout = (const float*)d_in[10];

  unsigned short* wp = (unsigned short*)d_ws;
  const size_t need = (size_t)(WPACK_SHORTS + XPACK_SHORTS) * 2;   // 15.1 MB

  pack_weights<<<832, 256, 0, stream>>>(wih0, whh0, wih1, whh1, wp);

  const unsigned short* xpk = nullptr;
  if (ws_size >= need) {
    unsigned short* xp = wp + WPACK_SHORTS;
    pack_x<<<(XPACK_SHORTS / 2 + 255) / 256, 256, 0, stream>>>(x, (unsigned*)xp);
    xpk = xp;
  }

  lstm_fused<<<256, 512, SMEM_SZ, stream>>>(x, wp, xpk, bih0, bhh0, bih1, bhh1,
                                            wout, bout, (float*)d_out);
}

// Round 15
// 199.036 us; speedup vs baseline: 1.0972x; 1.0399x over previous
//
#include <hip/hip_runtime.h>

// ---------------------------------------------------------------------------
// Fused 2-layer LSTM, N=8192, T=28, I=28, H=128, + final [128->10] linear.
// One block = 32 samples through all 28 timesteps of both layers.
// grid = 256 blocks x 512 threads (8 waves) -> 1 block/CU, 2 waves/SIMD.
//
// R15 = R14 (passing, 131.4us kernel / 207us bench) + two trims:
//  (1) pack_x DELETED: gap analysis showed it cost ~14us harness-level
//      (bench-minus-kernel gap 62us -> 76us when R11 added it) while the
//      in-loop alternative is now ~16 insts/interval via v_cvt_pk_bf16_f32
//      (2 dwordx4 loads + 4 cvt_pk per mt, hidden under the whh0 MFMAs).
//  (2) fused sigma*tanh products: sigma(a)*tanh(b) = (B-1)*rcp((1+A)(B+1)),
//      A=exp2(-a^), B=exp2(b^) -- one rcp instead of two for both the
//      i*g and o*tanh(c) products.  10 -> 8 trans/cell (trans = quarter
//      rate, the largest VALU component), +2 cheap VALU.  Range-safe:
//      |gates| <~ 6, |c^| <~ 81 -> all exp2 finite, rcp args normal.
//
// Structure (R11-R14, verified):
//   waves 0-3 = L0 specialists: whh0+wih0 (160 regs), own 32 dims each.
//   waves 4-7 = L1 specialists: whh1 (128 regs); wih1 read from LDS.
// Interval I: L0(t=I) and L1(t=I-1); 29 intervals, ONE barrier each.
// s_setprio(1) around MFMA clusters (R14, +3% in this role-split regime).
// exp2-domain gates (R12): pack_weights pre-scales sigma rows by log2e and
// g rows by 2log2e; biases stay in acc-init (R13 proved removing them
// costs stall).  h->bf16 via v_cvt_pk_bf16_f32.
// Race freedom (h0,h1 double-buffered): see R10/R11 analysis -- unchanged.
// LDS: wih1 131072 + h0 2x8192 + h1 2x8192 = 163840 (gfx950 max).
// ---------------------------------------------------------------------------

typedef short  short8   __attribute__((ext_vector_type(8)));
typedef float  float4_t __attribute__((ext_vector_type(4)));

#define WIH1_OFF 0        // 131072 B : w_ih1, persistent in LDS
#define H0_OFF   131072   // 2 x 8192 B : h0 double buffer
#define H1_OFF   147456   // 2 x 8192 B : h1 double buffer
#define SMEM_SZ  163840   // full 160 KiB LDS (dynamic alloc)

#define LOG2E  1.4426950408889634f
#define TLOG2E 2.8853900817779268f

__device__ __forceinline__ unsigned short bf16r(float v) {
  union { float f; unsigned u; } x; x.f = v;
  unsigned r = x.u + 0x7fffu + ((x.u >> 16) & 1u);   // round-to-nearest-even
  return (unsigned short)(r >> 16);
}
__device__ __forceinline__ float bf2f(unsigned short b) {
  union { unsigned u; float f; } x; x.u = ((unsigned)b) << 16;
  return x.f;
}
// exp2-domain sigmoid: xs = x * log2e (scale lives in weights/bias).
__device__ __forceinline__ float sig2(float xs) {
  return __builtin_amdgcn_rcpf(1.0f + __builtin_amdgcn_exp2f(-xs));
}
// fused sigma(a)*tanh(b): as = a*log2e, B = exp2(b*2log2e) precomputed.
// = (B-1) / ((1+exp2(-as)) * (B+1))  -- one rcp for the whole product.
__device__ __forceinline__ float sig_tanh2(float as, float B) {
  return (B - 1.0f) * __builtin_amdgcn_rcpf(
      (1.0f + __builtin_amdgcn_exp2f(-as)) * (B + 1.0f));
}
// pack two fp32 -> one dword of 2 bf16 (RTNE) in a single VALU inst
__device__ __forceinline__ unsigned cvt_pk_bf16(float lo, float hi) {
  unsigned u;
  asm("v_cvt_pk_bf16_f32 %0, %1, %2" : "=v"(u) : "v"(lo), "v"(hi));
  return u;
}

// ---------------------------------------------------------------------------
// Prologue: pack weights (fp32 -> bf16) into MFMA B-frag tiled layout in ws,
// pre-scaled into the exp2 domain (i,f,o rows x log2e; g rows x 2log2e).
// ws (unsigned short units):
//   [0      ,16384) : w_ih0  [1 kc][32 tiles][64 lanes][8]  (k padded to 32)
//   [16384  ,81920) : w_hh0  [4 kc][32 tiles][64][8]
//   [81920 ,147456) : w_ih1  [4 kc][32][64][8]
//   [147456,212992) : w_hh1  [4 kc][32][64][8]
// element (tile,lane,j): row = tile*16 + (lane&15), k = kc*32 + (lane>>4)*8 + j
// Gate of a row: tile>>3 (0=i,1=f,2=g,3=o).
// ---------------------------------------------------------------------------
__global__ void pack_weights(const float* __restrict__ wih0, const float* __restrict__ whh0,
                             const float* __restrict__ wih1, const float* __restrict__ whh1,
                             unsigned short* __restrict__ dst)
{
  int e = blockIdx.x * 256 + threadIdx.x;
  const float* src; int K; int i;
  if      (e < 16384)  { src = wih0; K = 28;  i = e;          }
  else if (e < 81920)  { src = whh0; K = 128; i = e - 16384;  }
  else if (e < 147456) { src = wih1; K = 128; i = e - 81920;  }
  else if (e < 212992) { src = whh1; K = 128; i = e - 147456; }
  else return;
  int j = i & 7, lane = (i >> 3) & 63, tile = (i >> 9) & 31, kc = i >> 14;
  int row = tile * 16 + (lane & 15);
  int k = kc * 32 + ((lane >> 4) << 3) + j;
  float v = (k < K) ? src[row * K + k] : 0.0f;
  float s = ((tile >> 3) == 2) ? TLOG2E : LOG2E;
  dst[e] = bf16r(v * s);
}

// ---------------------------------------------------------------------------
// Main fused kernel.
// ---------------------------------------------------------------------------
__global__ __launch_bounds__(512, 2)
void lstm_fused(const float* __restrict__ xg,
                const unsigned short* __restrict__ wpack,
                const float* __restrict__ bih0, const float* __restrict__ bhh0,
                const float* __restrict__ bih1, const float* __restrict__ bhh1,
                const float* __restrict__ wout, const float* __restrict__ bout,
                float* __restrict__ out)
{
  extern __shared__ __align__(16) char smem[];

  const int tid  = threadIdx.x;
  const int lane = tid & 63;
  const int wave = tid >> 6;          // 0..7
  const bool isL0 = (wave < 4);
  const int gw   = wave & 3;          // role-local: owns dims [gw*32, gw*32+32)
  const int q    = lane >> 4;         // quad: acc rows q*4 .. q*4+3
  const int mcol = lane & 15;         // acc col = h-dim within 16-dim group
  const int n0   = blockIdx.x * 32;   // batch tile base

  const short8* wp = (const short8*)wpack;

  // ---- persistent weights (role-specific) -------------------------------
  // L0 wave: whh0 for 2 dim-groups (128) + wih0 (32) = 160 regs.
  // L1 wave: whh1 for 2 dim-groups (128) regs; wih1 comes from LDS.
  short8 W[2][4][4];    // [dgi][kc][g]
  short8 WX[2][4];      // wih0 [dgi][g], L0 only
  if (isL0) {
#pragma unroll
    for (int dgi = 0; dgi < 2; ++dgi) {
      int dg = gw * 2 + dgi;
#pragma unroll
      for (int g = 0; g < 4; ++g)
        WX[dgi][g] = wp[(g * 8 + dg) * 64 + lane];
#pragma unroll
      for (int kc = 0; kc < 4; ++kc)
#pragma unroll
        for (int g = 0; g < 4; ++g)
          W[dgi][kc][g] = wp[ 2048 + (kc * 32 + g * 8 + dg) * 64 + lane];
    }
  } else {
#pragma unroll
    for (int dgi = 0; dgi < 2; ++dgi) {
      int dg = gw * 2 + dgi;
#pragma unroll
      for (int kc = 0; kc < 4; ++kc)
#pragma unroll
        for (int g = 0; g < 4; ++g)
          W[dgi][kc][g] = wp[18432 + (kc * 32 + g * 8 + dg) * 64 + lane];
    }
  }

  // ---- persistent w_ih1 in LDS (131072 B) --------------------------------
  {
    short8* dstp = (short8*)smem;
#pragma unroll
    for (int rr = 0; rr < 16; ++rr)
      dstp[rr * 512 + tid] = wp[10240 + rr * 512 + tid];
  }

  // ---- role biases (exp2-domain scaled; gate g, dgi dim-group) -----------
  float bias[2][4];
#pragma unroll
  for (int dgi = 0; dgi < 2; ++dgi) {
    const int d = (gw * 2 + dgi) * 16 + mcol;
#pragma unroll
    for (int g = 0; g < 4; ++g) {
      float b = isL0 ? (bih0[g * 128 + d] + bhh0[g * 128 + d])
                     : (bih1[g * 128 + d] + bhh1[g * 128 + d]);
      bias[dgi][g] = b * ((g == 2) ? TLOG2E : LOG2E);
    }
  }

  // ---- zero the "B" halves of h0/h1 (read as h_{-1}) ---------------------
  {
    int* z0 = (int*)(smem + H0_OFF + 8192);
    int* z1 = (int*)(smem + H1_OFF + 8192);
#pragma unroll
    for (int rr = 0; rr < 4; ++rr) { z0[rr * 512 + tid] = 0; z1[rr * 512 + tid] = 0; }
  }

  __syncthreads();   // wih1 + zeros visible

  const short8* W1f = (const short8*)(smem + WIH1_OFF);

  // per-lane constant h-write addresses for the wave's two dim-groups:
  int hconst[2];
#pragma unroll
  for (int dgi = 0; dgi < 2; ++dgi)
    hconst[dgi] = gw * 1024 + (((dgi << 1) | (mcol >> 3)) * 256) + q * 64 + (mcol & 7) * 2;

  float cc[2][2][4] = {{{0.f,0.f,0.f,0.f},{0.f,0.f,0.f,0.f}},
                       {{0.f,0.f,0.f,0.f},{0.f,0.f,0.f,0.f}}};

#pragma unroll 1
  for (int I = 0; I < 29; ++I) {
    if (isL0) {
      if (I < 28) {
        // ---- LAYER 0, t = I: gates = b0 + h0_{t-1}@Whh0^T + x_t@Wih0^T ----
        const short8* H0R = (const short8*)(smem + H0_OFF + (((I + 1) & 1) << 13));
        char*         h0w = smem + H0_OFF + ((I & 1) << 13);

        // x_t: direct global loads + cvt_pk conversion (no pack_x kernel).
        // lane holds x[n0+mt*16+mcol][I*28 + q*8 + j], j=0..7 (k pad -> 0).
        short8 xf[2];
#pragma unroll
        for (int mt = 0; mt < 2; ++mt) {
          const float* xsrc = xg + (size_t)(n0 + mt * 16 + mcol) * 784 + I * 28 + q * 8;
          float4_t xa = *(const float4_t*)xsrc;
          const float* x2 = xsrc + ((q == 3) ? 0 : 4);   // clamp: stay in-bounds
          float4_t xb = *(const float4_t*)x2;
          if (q == 3) xb = (float4_t){0.f, 0.f, 0.f, 0.f};
          union { short8 s; unsigned u[4]; } U;
          U.u[0] = cvt_pk_bf16(xa[0], xa[1]);
          U.u[1] = cvt_pk_bf16(xa[2], xa[3]);
          U.u[2] = cvt_pk_bf16(xb[0], xb[1]);
          U.u[3] = cvt_pk_bf16(xb[2], xb[3]);
          xf[mt] = U.s;
        }

#pragma unroll
        for (int dgi = 0; dgi < 2; ++dgi)
#pragma unroll
          for (int mt = 0; mt < 2; ++mt) {
            float4_t acc[4];
#pragma unroll
            for (int g = 0; g < 4; ++g)
              acc[g] = (float4_t){bias[dgi][g], bias[dgi][g], bias[dgi][g], bias[dgi][g]};
            // MFMA cluster at raised priority (T5, role-split regime).
            __builtin_amdgcn_s_setprio(1);
#pragma unroll
            for (int kc = 0; kc < 4; ++kc) {
              short8 hf = H0R[(mt * 4 + kc) * 64 + lane];
#pragma unroll
              for (int g = 0; g < 4; ++g)
                acc[g] = __builtin_amdgcn_mfma_f32_16x16x32_bf16(hf, W[dgi][kc][g], acc[g], 0, 0, 0);
            }
#pragma unroll
            for (int g = 0; g < 4; ++g)
              acc[g] = __builtin_amdgcn_mfma_f32_16x16x32_bf16(xf[mt], WX[dgi][g], acc[g], 0, 0, 0);
            __builtin_amdgcn_s_setprio(0);
            // activations: 8 trans/cell (fused sigma*tanh products)
            float hv[4];
#pragma unroll
            for (int r = 0; r < 4; ++r) {
              float Bg = __builtin_amdgcn_exp2f(acc[2][r]);           // g: 2log2e-scaled
              float c  = sig2(acc[1][r]) * cc[dgi][mt][r] + sig_tanh2(acc[0][r], Bg);
              cc[dgi][mt][r] = c;
              float Bc = __builtin_amdgcn_exp2f(c * TLOG2E);
              hv[r] = sig_tanh2(acc[3][r], Bc);
            }
            unsigned u01 = cvt_pk_bf16(hv[0], hv[1]);
            unsigned u23 = cvt_pk_bf16(hv[2], hv[3]);
            char* base = h0w + mt * 4096 + hconst[dgi];
            *(unsigned short*)(base +  0) = (unsigned short)u01;
            *(unsigned short*)(base + 16) = (unsigned short)(u01 >> 16);
            *(unsigned short*)(base + 32) = (unsigned short)u23;
            *(unsigned short*)(base + 48) = (unsigned short)(u23 >> 16);
          }
      }
    } else {
      if (I > 0) {
        // ---- LAYER 1, t = I-1: gates = b1 + h1_{t-1}@Whh1^T + h0_t@Wih1^T -
        const short8* H0S = (const short8*)(smem + H0_OFF + (((I - 1) & 1) << 13));
        const short8* H1R = (const short8*)(smem + H1_OFF + ((I & 1) << 13));
        char*         h1w = smem + H1_OFF + (((I - 1) & 1) << 13);
#pragma unroll
        for (int dgi = 0; dgi < 2; ++dgi) {
          int dg = gw * 2 + dgi;
          float4_t acc[2][4];
#pragma unroll
          for (int mt = 0; mt < 2; ++mt)
#pragma unroll
            for (int g = 0; g < 4; ++g)
              acc[mt][g] = (float4_t){bias[dgi][g], bias[dgi][g], bias[dgi][g], bias[dgi][g]};
          __builtin_amdgcn_s_setprio(1);   // MFMA cluster (T5)
          // reg-weight whh1 MFMAs first
#pragma unroll
          for (int kc = 0; kc < 4; ++kc)
#pragma unroll
            for (int mt = 0; mt < 2; ++mt) {
              short8 hf = H1R[(mt * 4 + kc) * 64 + lane];
#pragma unroll
              for (int g = 0; g < 4; ++g)
                acc[mt][g] = __builtin_amdgcn_mfma_f32_16x16x32_bf16(hf, W[dgi][kc][g], acc[mt][g], 0, 0, 0);
            }
          // wih1 from LDS
#pragma unroll
          for (int kc = 0; kc < 4; ++kc) {
            short8 wf[4];
#pragma unroll
            for (int g = 0; g < 4; ++g)
              wf[g] = W1f[(kc * 32 + g * 8 + dg) * 64 + lane];
#pragma unroll
            for (int mt = 0; mt < 2; ++mt) {
              short8 hf = H0S[(mt * 4 + kc) * 64 + lane];
#pragma unroll
              for (int g = 0; g < 4; ++g)
                acc[mt][g] = __builtin_amdgcn_mfma_f32_16x16x32_bf16(hf, wf[g], acc[mt][g], 0, 0, 0);
            }
          }
          __builtin_amdgcn_s_setprio(0);
          // activations; write h1_t directly (race-free)
#pragma unroll
          for (int mt = 0; mt < 2; ++mt) {
            float hv[4];
#pragma unroll
            for (int r = 0; r < 4; ++r) {
              float Bg = __builtin_amdgcn_exp2f(acc[mt][2][r]);
              float c  = sig2(acc[mt][1][r]) * cc[dgi][mt][r] + sig_tanh2(acc[mt][0][r], Bg);
              cc[dgi][mt][r] = c;
              float Bc = __builtin_amdgcn_exp2f(c * TLOG2E);
              hv[r] = sig_tanh2(acc[mt][3][r], Bc);
            }
            unsigned u01 = cvt_pk_bf16(hv[0], hv[1]);
            unsigned u23 = cvt_pk_bf16(hv[2], hv[3]);
            char* base = h1w + mt * 4096 + hconst[dgi];
            *(unsigned short*)(base +  0) = (unsigned short)u01;
            *(unsigned short*)(base + 16) = (unsigned short)(u01 >> 16);
            *(unsigned short*)(base + 32) = (unsigned short)u23;
            *(unsigned short*)(base + 48) = (unsigned short)(u23 >> 16);
          }
        }
      }
    }
    __syncthreads();   // THE barrier: ends interval I
  }

  // ================= epilogue: out[s][o] = h1 . wout[o] + bout[o] =========
  // h1(27) was written in interval 28 to buffer 1.
  if (tid < 320) {
    const short8* H1f = (const short8*)(smem + H1_OFF + 8192);
    int s = tid / 10, o = tid - (tid / 10) * 10;
    float sum = bout[o];
#pragma unroll
    for (int kc = 0; kc < 4; ++kc)
#pragma unroll
      for (int sb = 0; sb < 4; ++sb) {
        short8 hv = H1f[((s >> 4) * 4 + kc) * 64 + sb * 16 + (s & 15)];
        int dbase = kc * 32 + sb * 8;
        float4_t w0 = *(const float4_t*)(wout + o * 128 + dbase);
        float4_t w1 = *(const float4_t*)(wout + o * 128 + dbase + 4);
#pragma unroll
        for (int j = 0; j < 4; ++j) {
          sum += bf2f((unsigned short)hv[j])     * w0[j];
          sum += bf2f((unsigned short)hv[j + 4]) * w1[j];
        }
      }
    out[(size_t)(n0 + s) * 10 + o] = sum;
  }
}

extern "C" void kernel_launch(void* const* d_in, const int* in_sizes, int n_in,
                              void* d_out, int out_size, void* d_ws, size_t ws_size,
                              hipStream_t stream) {
  const float* x    = (const float*)d_in[0];
  const float* wih0 = (const float*)d_in[1];
  const float* whh0 = (const float*)d_in[2];
  const float* bih0 = (const float*)d_in[3];
  const float* bhh0 = (const float*)d_in[4];
  const float* wih1 = (const float*)d_in[5];
  const float* whh1 = (const float*)d_in[6];
  const float* bih1 = (const float*)d_in[7];
  const float* bhh1 = (const float*)d_in[8];
  const float* wout = (const float*)d_in[9];
  const float* bout = (const float*)d_in[10];

  unsigned short* wp = (unsigned short*)d_ws;   // 425984 B used

  pack_weights<<<832, 256, 0, stream>>>(wih0, whh0, wih1, whh1, wp);
  lstm_fused<<<256, 512, SMEM_SZ, stream>>>(x, wp, bih0, bhh0, bih1, bhh1,
                                            wout, bout, (float*)d_out);
}